// Round 4
// baseline (193.376 us; speedup 1.0000x reference)
//
#include <hip/hip_runtime.h>

#define GH 721
#define GW 1440
#define NLVL 8

typedef float vf2 __attribute__((ext_vector_type(2)));
typedef float vf4 __attribute__((ext_vector_type(4)));

// One thread per point, all 8 pyramid levels unrolled.
// Phase 1: compute all addresses, issue all 16 gather loads (paired columns
//          as unaligned float2 -> one global_load_dwordx2 per row probe).
// sched_barrier(0): forbid the compiler from sinking loads into the consume
//          phase (it did: VGPR=32 -> only ~2 loads in flight, latency-bound).
// Phase 2: arithmetic + coalesced nontemporal float4 stores.
// inv = 1/(0.25*2^l) is an exact power of two -> mul == reference's division.
__global__ __launch_bounds__(256) void coolchic_interp_kernel(
    const float* __restrict__ x,
    const float* __restrict__ emb,
    float* __restrict__ out,
    int n)
{
    int i = blockIdx.x * blockDim.x + threadIdx.x;
    if (i >= n) return;

    vf2 p = __builtin_nontemporal_load(reinterpret_cast<const vf2*>(x) + i);
    float lat_num = 90.0f - p.x;   // >= 0
    float lon     = p.y;           // [0, 360)

    vf2   pf[NLVL];   // (g[laf][c], g[laf][c+1])
    vf2   pc[NLVL];   // (g[lac][c], g[lac][c+1])
    float fla[NLVL], flo[NLVL];
    int   edge[NLVL];

    float inv = 4.0f;
    #pragma unroll
    for (int l = 0; l < NLVL; ++l) {
        float latf = lat_num * inv;
        float lonf = lon * inv;
        int la = (int)latf;          // >=0 -> trunc == floor
        int lo = (int)lonf;          // lo <= GW-1 always (lon < 360)
        int laf = min(la,     GH - 1);
        int lac = min(la + 1, GH - 1);
        int c   = min(lo,     GW - 2);   // pair (c, c+1) always in-bounds
        // fractions use CLAMPED floor indices (reference quirk); lof==lo here
        fla[l]  = latf - (float)laf;
        flo[l]  = lonf - (float)lo;
        edge[l] = (lo > GW - 2);

        const float* g = emb + (size_t)l * (GH * GW);
        pf[l] = *reinterpret_cast<const vf2*>(g + laf * GW + c);
        pc[l] = *reinterpret_cast<const vf2*>(g + lac * GW + c);
        inv *= 0.5f;
    }

    // Keep all 16 gathers issued before any consumer: nothing crosses this.
    __builtin_amdgcn_sched_barrier(0);

    float o[NLVL];
    #pragma unroll
    for (int l = 0; l < NLVL; ++l) {
        float vff = edge[l] ? pf[l].y : pf[l].x;
        float vfc = pf[l].y;
        float vcf = edge[l] ? pc[l].y : pc[l].x;
        float vcc = pc[l].y;
        float vf = vff + flo[l] * (vfc - vff);
        float vc = vcf + flo[l] * (vcc - vcf);
        o[l] = vf + fla[l] * (vc - vf);
    }

    vf4* o4 = reinterpret_cast<vf4*>(out + (size_t)i * NLVL);
    vf4 o_lo = { o[0], o[1], o[2], o[3] };
    vf4 o_hi = { o[4], o[5], o[6], o[7] };
    __builtin_nontemporal_store(o_lo, o4);
    __builtin_nontemporal_store(o_hi, o4 + 1);
}

extern "C" void kernel_launch(void* const* d_in, const int* in_sizes, int n_in,
                              void* d_out, int out_size, void* d_ws, size_t ws_size,
                              hipStream_t stream) {
    const float* x   = (const float*)d_in[0];   // [N, 2]
    const float* emb = (const float*)d_in[1];   // [8, 721, 1440]
    float* out = (float*)d_out;                 // [N, 8]
    int n = in_sizes[0] / 2;

    int block = 256;
    int grid = (n + block - 1) / block;
    coolchic_interp_kernel<<<grid, block, 0, stream>>>(x, emb, out, n);
}

// Round 9
// 174.137 us; speedup vs baseline: 1.1105x; 1.1105x over previous
//
#include <hip/hip_runtime.h>

#define GH 721
#define GW 1440
#define NLVL 8

typedef float vf2 __attribute__((ext_vector_type(2)));
typedef float vf4 __attribute__((ext_vector_type(4)));

// Exact LDS tile dims for levels 4..7.
// At level l: lat_idx = (90-lat)*4/2^l <= 720/2^l (reachable), lon_idx < 1440/2^l.
// Scaling is by exact powers of two -> bounds are exact in fp32.
// rows = floor(720/2^l)+2 (la and la+1); cols = (max lo)+2.
#define R4 47
#define C4 91
#define R5 24
#define C5 46
#define R6 13
#define C6 24
#define R7 7
#define C7 13
#define T4 (R4*C4)   // 4277
#define T5 (R5*C5)   // 1104
#define T6 (R6*C6)   // 312  (> 256: MUST use strided loop to stage!)
#define T7 (R7*C7)   // 91   -> total 5784 floats = 22.6 KB

// Grid-stride over 256-point chunks. Levels 4..7 are gathered from LDS
// (no TA transactions); levels 0..3 from global. Levels >=1 can never hit
// the lat/lon clamps (index < grid dims by construction), so their
// clamp/edge logic is removed entirely.
__global__ __launch_bounds__(256) void coolchic_interp_kernel(
    const float* __restrict__ x,
    const float* __restrict__ emb,
    float* __restrict__ out,
    int n, int nchunks)
{
    __shared__ float t4[T4];
    __shared__ float t5[T5];
    __shared__ float t6[T6];
    __shared__ float t7[T7];

    const int tid = threadIdx.x;

    // ---- stage levels 4..7 into LDS (once per block) ----
    {
        const float* g4 = emb + 4 * (size_t)(GH * GW);
        for (int idx = tid; idx < T4; idx += 256) {
            int r = idx / C4, c = idx - r * C4;
            t4[idx] = g4[r * GW + c];
        }
        const float* g5 = emb + 5 * (size_t)(GH * GW);
        for (int idx = tid; idx < T5; idx += 256) {
            int r = idx / C5, c = idx - r * C5;
            t5[idx] = g5[r * GW + c];
        }
        const float* g6 = emb + 6 * (size_t)(GH * GW);
        for (int idx = tid; idx < T6; idx += 256) {
            int r = idx / C6, c = idx - r * C6;
            t6[idx] = g6[r * GW + c];
        }
        const float* g7 = emb + 7 * (size_t)(GH * GW);
        if (tid < T7) {
            int r = tid / C7, c = tid - r * C7;
            t7[tid] = g7[r * GW + c];
        }
    }
    __syncthreads();

    for (int chunk = blockIdx.x; chunk < nchunks; chunk += gridDim.x) {
        int i = chunk * 256 + tid;
        if (i >= n) continue;

        vf2 p = __builtin_nontemporal_load(reinterpret_cast<const vf2*>(x) + i);
        float lat_num = 90.0f - p.x;   // [0, 180]
        float lon     = p.y;           // [0, 360)

        float o[NLVL];

        // ---- level 0: lon edge + lat ceil clamp possible ----
        {
            float latf = lat_num * 4.0f;     // <= 720
            float lonf = lon * 4.0f;         // < 1440
            int la = (int)latf;              // <= 720 == GH-1, no clamp needed
            int lo = (int)lonf;              // <= 1439
            int lac = min(la + 1, GH - 1);
            int c   = min(lo, GW - 2);       // pair (c, c+1) in-bounds
            float fla = latf - (float)la;
            float flo = lonf - (float)lo;    // ref uses clamped floor = lo here
            bool edge = lo > GW - 2;
            const float* r0 = emb + la  * GW + c;
            const float* r1 = emb + lac * GW + c;
            vf2 pf = *reinterpret_cast<const vf2*>(r0);
            vf2 pc = *reinterpret_cast<const vf2*>(r1);
            float vff = edge ? pf.y : pf.x;
            float vcf = edge ? pc.y : pc.x;
            float vf_ = vff + flo * (pf.y - vff);
            float vc_ = vcf + flo * (pc.y - vcf);
            o[0] = vf_ + fla * (vc_ - vf_);
        }

        // ---- levels 1..3: no clamping possible ----
        float inv = 2.0f;
        #pragma unroll
        for (int l = 1; l <= 3; ++l) {
            float latf = lat_num * inv;
            float lonf = lon * inv;
            int la = (int)latf;
            int lo = (int)lonf;
            float fla = latf - (float)la;
            float flo = lonf - (float)lo;
            const float* r0 = emb + (size_t)l * (GH * GW) + la * GW + lo;
            vf2 pf = *reinterpret_cast<const vf2*>(r0);
            vf2 pc = *reinterpret_cast<const vf2*>(r0 + GW);
            float vf_ = pf.x + flo * (pf.y - pf.x);
            float vc_ = pc.x + flo * (pc.y - pc.x);
            o[l] = vf_ + fla * (vc_ - vf_);
            inv *= 0.5f;
        }

        // ---- levels 4..7: gather from LDS ----
        // inv is now 0.25 (level 4)
        {
            const float* tl[4] = { t4, t5, t6, t7 };
            const int    cl[4] = { C4, C5, C6, C7 };
            #pragma unroll
            for (int k = 0; k < 4; ++k) {
                float latf = lat_num * inv;
                float lonf = lon * inv;
                int la = (int)latf;
                int lo = (int)lonf;
                float fla = latf - (float)la;
                float flo = lonf - (float)lo;
                const float* r0 = tl[k] + la * cl[k] + lo;
                float pf0 = r0[0];
                float pf1 = r0[1];
                float pc0 = r0[cl[k]];
                float pc1 = r0[cl[k] + 1];
                float vf_ = pf0 + flo * (pf1 - pf0);
                float vc_ = pc0 + flo * (pc1 - pc0);
                o[4 + k] = vf_ + fla * (vc_ - vf_);
                inv *= 0.5f;
            }
        }

        vf4* o4 = reinterpret_cast<vf4*>(out + (size_t)i * NLVL);
        vf4 o_lo = { o[0], o[1], o[2], o[3] };
        vf4 o_hi = { o[4], o[5], o[6], o[7] };
        __builtin_nontemporal_store(o_lo, o4);
        __builtin_nontemporal_store(o_hi, o4 + 1);
    }
}

extern "C" void kernel_launch(void* const* d_in, const int* in_sizes, int n_in,
                              void* d_out, int out_size, void* d_ws, size_t ws_size,
                              hipStream_t stream) {
    const float* x   = (const float*)d_in[0];   // [N, 2]
    const float* emb = (const float*)d_in[1];   // [8, 721, 1440]
    float* out = (float*)d_out;                 // [N, 8]
    int n = in_sizes[0] / 2;
    int nchunks = (n + 255) / 256;

    // ~7 blocks/CU (LDS 22.6KB -> 7 resident), grid-stride over chunks.
    int grid = 1792;
    if (grid > nchunks) grid = nchunks;
    coolchic_interp_kernel<<<grid, 256, 0, stream>>>(x, emb, out, n, nchunks);
}